// Round 9
// baseline (404.281 us; speedup 1.0000x reference)
//
#include <hip/hip_runtime.h>

// VQ-VAE VectorQuantizer: B=32, C=D=64, H=W=64, K=512
// d_in[0]: inputs  [32,64,64,64] f32 (NCHW, C = embedding dim)
// d_in[1]: embedding [512,64] f32
// d_out: [loss(1) | out(32*64*64*64) | indices(32*4096)] all read as f32
//
// V9: scratch-free writer + higher-concurrency screen.
// V8 post-mortem: writer's `h ? xo : xh` runtime pointer-select forced both
// register arrays to scratch (VGPR dropped to 80 BECAUSE arrays left the RF);
// hot-path xh reads became scratch loads -> 230us at 1.6% VALUBusy. Fix:
// branch-duplicated resolve with static array args (h==0 uses (xh,xo),
// h==1 uses (xo,xh) -> bitwise-identical values, no pointer select).
// Cross-round ledger also shows screen ~= 100us (V6/V7b/V8 all carry
// ~115us prep+screen): pt=2's serial MFMA->INS chain at <=12 waves/CU is
// latency-stretched. Fix: pt=1 (16 pos/wave), grid 2048, no bounds cap ->
// ~20 waves/CU, half the per-wave serial work.
//   vq_prep:   e2 (numpy order) + bf16 hi/lo B-fragments + zeroing.
//   vq_screen: single MFMA sweep, in-register top-4 (m1..m4, i1..i3);
//              packs {i1,i2,i3,g2,g3,g4} into out_idx bits (__uint_as_float).
//   vq_write:  2 threads/position; g2/g3: lane-local 2-3 candidate exact;
//              g4 (~never): loop-based pair-split half-scan. Loss via
//              per-block float atomicAdd + ticket (V5-proven at tolerance).
// Correctness: screen error on score differences <= ~1e-4 < DELTA=2.5e-4;
// numpy argmin is in the candidate set unless the next g-flag is set (strict-<
// INS4 escalates boundary ties). Exact path = round-0-proven fmaf/pairwise-8
// ordering, lexicographic (u,k) min == numpy first-min.

#define KCODE 512
#define EMB   64
#define HWSZ  4096
#define NPOS  131072
#define DELTA 2.5e-4f

typedef short short8  __attribute__((ext_vector_type(8)));
typedef float float4v __attribute__((ext_vector_type(4)));

// ws float layout:
//   [0]           loss accumulator (float, atomicAdd)
//   [1]           writer ticket (uint)
//   [1032..1543]  e2 (numpy rounding, by code)
//   [1544..34311] bfrag short8[32][2][2][64] (128 KB)

// ---------- numpy-exact helpers ----------
__device__ __forceinline__ float np_sumsq64(const float* a) {
    #pragma clang fp contract(off)
    {
        float r0 = a[0] * a[0], r1 = a[1] * a[1], r2 = a[2] * a[2], r3 = a[3] * a[3];
        float r4 = a[4] * a[4], r5 = a[5] * a[5], r6 = a[6] * a[6], r7 = a[7] * a[7];
        for (int i = 8; i < 64; i += 8) {
            r0 += a[i + 0] * a[i + 0];
            r1 += a[i + 1] * a[i + 1];
            r2 += a[i + 2] * a[i + 2];
            r3 += a[i + 3] * a[i + 3];
            r4 += a[i + 4] * a[i + 4];
            r5 += a[i + 5] * a[i + 5];
            r6 += a[i + 6] * a[i + 6];
            r7 += a[i + 7] * a[i + 7];
        }
        return ((r0 + r1) + (r2 + r3)) + ((r4 + r5) + (r6 + r7));
    }
}

// split halves, identical accumulation order (a = dims 0..31, o = 32..63).
// ALWAYS called with static array identities (no pointer select).
__device__ __forceinline__ float np_sumsq64_split(const float* a, const float* o) {
    #pragma clang fp contract(off)
    {
        float r0 = a[0] * a[0], r1 = a[1] * a[1], r2 = a[2] * a[2], r3 = a[3] * a[3];
        float r4 = a[4] * a[4], r5 = a[5] * a[5], r6 = a[6] * a[6], r7 = a[7] * a[7];
        for (int i = 8; i < 32; i += 8) {
            r0 += a[i + 0] * a[i + 0];  r1 += a[i + 1] * a[i + 1];
            r2 += a[i + 2] * a[i + 2];  r3 += a[i + 3] * a[i + 3];
            r4 += a[i + 4] * a[i + 4];  r5 += a[i + 5] * a[i + 5];
            r6 += a[i + 6] * a[i + 6];  r7 += a[i + 7] * a[i + 7];
        }
        for (int i = 0; i < 32; i += 8) {
            r0 += o[i + 0] * o[i + 0];  r1 += o[i + 1] * o[i + 1];
            r2 += o[i + 2] * o[i + 2];  r3 += o[i + 3] * o[i + 3];
            r4 += o[i + 4] * o[i + 4];  r5 += o[i + 5] * o[i + 5];
            r6 += o[i + 6] * o[i + 6];  r7 += o[i + 7] * o[i + 7];
        }
        return ((r0 + r1) + (r2 + r3)) + ((r4 + r5) + (r6 + r7));
    }
}

// exact numpy distance with split-half x: u = fl(fl(x2 - 2*xe) + e2k)
// (identical accumulation order to the round-0-proven exact_u)
__device__ __forceinline__ float exact_u_split2(const float* a, const float* o,
                                                float x2, const float* ek,
                                                float e2k) {
    float t0 = 0.f, t1 = 0.f, t2 = 0.f, t3 = 0.f;
    #pragma unroll
    for (int c = 0; c < 32; c += 4) {
        t0 = fmaf(a[c + 0], ek[c + 0], t0);
        t1 = fmaf(a[c + 1], ek[c + 1], t1);
        t2 = fmaf(a[c + 2], ek[c + 2], t2);
        t3 = fmaf(a[c + 3], ek[c + 3], t3);
    }
    #pragma unroll
    for (int c = 0; c < 32; c += 4) {
        t0 = fmaf(o[c + 0], ek[32 + c + 0], t0);
        t1 = fmaf(o[c + 1], ek[32 + c + 1], t1);
        t2 = fmaf(o[c + 2], ek[32 + c + 2], t2);
        t3 = fmaf(o[c + 3], ek[32 + c + 3], t3);
    }
    float xe  = (t0 + t1) + (t2 + t3);
    float tmp = x2 - 2.0f * xe;
    return tmp + e2k;
}

__device__ __forceinline__ unsigned short bf16rne(float f) {
    unsigned u = __float_as_uint(f);
    unsigned r = (u + 0x7FFFu + ((u >> 16) & 1u)) >> 16;
    return (unsigned short)r;
}
__device__ __forceinline__ float bf16tof(unsigned short h) {
    return __uint_as_float((unsigned)h << 16);
}

// sorted-insert of (v,i) into ((M1,I1),(M2,I2),(M3,I3),M4); strict < keeps
// earlier element on ties (boundary ties escalate the next g-flag instead).
#define INS4(M1, I1, M2, I2, M3, I3, M4, v, i)                       \
    {                                                                \
        bool lt1 = (v) < (M1), lt2 = (v) < (M2);                     \
        bool lt3 = (v) < (M3), lt4 = (v) < (M4);                     \
        (M4) = lt3 ? (M3) : (lt4 ? (v) : (M4));                      \
        (I3) = lt2 ? (I2) : (lt3 ? (i) : (I3));                      \
        (M3) = lt2 ? (M2) : (lt3 ? (v) : (M3));                      \
        (I2) = lt1 ? (I1) : (lt2 ? (i) : (I2));                      \
        (M2) = lt1 ? (M1) : (lt2 ? (v) : (M2));                      \
        (I1) = lt1 ? (i) : (I1);                                     \
        (M1) = lt1 ? (v) : (M1);                                     \
    }

// ---------- prep: e2 + bfrag + zeroing ----------
__global__ void vq_prep(const float* __restrict__ emb, float* __restrict__ ws) {
    int f = blockIdx.x * blockDim.x + threadIdx.x;   // 0..4095
    if (f == 0) { ws[0] = 0.0f; ((unsigned*)ws)[1] = 0u; }
    if (f < KCODE) ws[1032 + f] = np_sumsq64(emb + f * EMB);
    short8* bfrag = (short8*)(ws + 1544);
    int l = f & 63;
    int c = (f >> 6) & 1;
    int t = f >> 7;            // 0..31
    int code  = t * 16 + (l & 15);
    int dbase = 32 * c + ((l >> 4) & 3) * 8;
    const float* e = emb + code * EMB + dbase;
    short8 h, lo;
    #pragma unroll
    for (int j = 0; j < 8; ++j) {
        float v = e[j];
        unsigned short hb = bf16rne(v);
        float hf = bf16tof(hb);
        unsigned short lb = bf16rne(v - hf);
        h[j]  = (short)hb;
        lo[j] = (short)lb;
    }
    bfrag[t * 256 + c * 128 + 0 * 64 + l] = h;
    bfrag[t * 256 + c * 128 + 1 * 64 + l] = lo;
}

// ---------- screen: pt=1, single MFMA sweep, top-4 tracking ----------
__global__ __launch_bounds__(256) void vq_screen(
        const float*  __restrict__ in,
        const float*  __restrict__ e2np,      // ws+1032
        const short8* __restrict__ bfrag,     // ws+1544
        float*        __restrict__ out_idx) { // bit-packed {i1,i2,i3,flags}
    const int tid  = threadIdx.x;
    const int wave = tid >> 6;
    const int lane = tid & 63;
    const int lg   = lane >> 4;
    const int lc   = lane & 15;
    const int wavePos = blockIdx.x * 64 + wave * 16;   // 16 positions/wave

    // A-fragments: 1 pos-tile x 2 dim-chunks, hi/lo of g = -2x.
    // A element j of lane: row = lane&15 (position), k-dim = (lane>>4)*8+j.
    short8 fH[2], fL[2];
    {
        int pos = wavePos + lc;
        int b   = pos >> 12;
        int hw  = pos & (HWSZ - 1);
        const float* xb = in + ((size_t)b << 18) + hw;
        #pragma unroll
        for (int c = 0; c < 2; ++c) {
            short8 h, lo;
            #pragma unroll
            for (int j = 0; j < 8; ++j) {
                int d = 32 * c + lg * 8 + j;
                float g = -2.0f * xb[(size_t)d << 12];
                unsigned short hb = bf16rne(g);
                float hf = bf16tof(hb);
                unsigned short lb = bf16rne(g - hf);
                h[j]  = (short)hb;
                lo[j] = (short)lb;
            }
            fH[c] = h;
            fL[c] = lo;
        }
    }

    float m1[4], m2[4], m3[4], m4[4];
    int   i1[4], i2[4], i3[4];
    #pragma unroll
    for (int r = 0; r < 4; ++r) {
        m1[r] = 3.4e38f; m2[r] = 3.4e38f; m3[r] = 3.4e38f; m4[r] = 3.4e38f;
        i1[r] = 0; i2[r] = 0; i3[r] = 0;
    }

    short8 ceh0 = bfrag[lane],       cel0 = bfrag[64 + lane];
    short8 ceh1 = bfrag[128 + lane], cel1 = bfrag[192 + lane];
    float  ce2  = e2np[lc];
    #pragma unroll 2
    for (int t = 0; t < 32; ++t) {
        short8 neh0, nel0, neh1, nel1;
        float  ne2 = 0.0f;
        if (t < 31) {
            const short8* nb = bfrag + (t + 1) * 256;
            neh0 = nb[lane];       nel0 = nb[64 + lane];
            neh1 = nb[128 + lane]; nel1 = nb[192 + lane];
            ne2  = e2np[(t + 1) * 16 + lc];
        }
        const int kf = t * 16 + lc;
        float4v aH = {ce2, ce2, ce2, ce2};
        float4v aM = {0.f, 0.f, 0.f, 0.f};
        float4v aL = {0.f, 0.f, 0.f, 0.f};
        aH = __builtin_amdgcn_mfma_f32_16x16x32_bf16(fH[0], ceh0, aH, 0, 0, 0);
        aM = __builtin_amdgcn_mfma_f32_16x16x32_bf16(fH[0], cel0, aM, 0, 0, 0);
        aL = __builtin_amdgcn_mfma_f32_16x16x32_bf16(fL[0], ceh0, aL, 0, 0, 0);
        aH = __builtin_amdgcn_mfma_f32_16x16x32_bf16(fH[1], ceh1, aH, 0, 0, 0);
        aM = __builtin_amdgcn_mfma_f32_16x16x32_bf16(fH[1], cel1, aM, 0, 0, 0);
        aL = __builtin_amdgcn_mfma_f32_16x16x32_bf16(fL[1], ceh1, aL, 0, 0, 0);
        #pragma unroll
        for (int r = 0; r < 4; ++r) {
            float sv = (aH[r] + aM[r]) + aL[r];
            INS4(m1[r], i1[r], m2[r], i2[r], m3[r], i3[r], m4[r], sv, kf);
        }
        ceh0 = neh0; cel0 = nel0; ceh1 = neh1; cel1 = nel1; ce2 = ne2;
    }

    // cross-lane top-4 merge over the 16-lane code group. Partner's m4 can
    // never rank <=3 in the union (its own m1..m3 are smaller), so value-only
    // min into M4 after the three indexed inserts is exact.
    #pragma unroll
    for (int r = 0; r < 4; ++r) {
        float M1 = m1[r], M2 = m2[r], M3 = m3[r], M4 = m4[r];
        int   I1 = i1[r], I2 = i2[r], I3 = i3[r];
        #pragma unroll
        for (int d = 1; d <= 8; d <<= 1) {
            float pm1 = __shfl_xor(M1, d, 64);
            int   pi1 = __shfl_xor(I1, d, 64);
            float pm2 = __shfl_xor(M2, d, 64);
            int   pi2 = __shfl_xor(I2, d, 64);
            float pm3 = __shfl_xor(M3, d, 64);
            int   pi3 = __shfl_xor(I3, d, 64);
            float pm4 = __shfl_xor(M4, d, 64);
            INS4(M1, I1, M2, I2, M3, I3, M4, pm1, pi1);
            INS4(M1, I1, M2, I2, M3, I3, M4, pm2, pi2);
            INS4(M1, I1, M2, I2, M3, I3, M4, pm3, pi3);
            M4 = fminf(M4, pm4);
        }
        m1[r] = M1; m2[r] = M2; m3[r] = M3; m4[r] = M4;
        i1[r] = I1; i2[r] = I2; i3[r] = I3;
    }

    if (lc == 0) {
        #pragma unroll
        for (int r = 0; r < 4; ++r) {
            int p = wavePos + lg * 4 + r;
            unsigned g2 = (m2[r] - m1[r] <= DELTA) ? 1u : 0u;
            unsigned g3 = (m3[r] - m1[r] <= DELTA) ? 1u : 0u;
            unsigned g4 = (m4[r] - m1[r] <= DELTA) ? 1u : 0u;
            unsigned packed = (unsigned)i1[r]
                            | ((unsigned)i2[r] << 9)
                            | ((unsigned)i3[r] << 18)
                            | (g2 << 27) | (g3 << 28) | (g4 << 29);
            out_idx[p] = __uint_as_float(packed);   // bit store, not cast
        }
    }
}

// ---------- writer: 2 threads/position; static-array resolves ----------
__global__ __launch_bounds__(256) void vq_write(
        const float* __restrict__ in, const float* __restrict__ emb,
        const float* __restrict__ e2np,
        float* __restrict__ out_idx, float* __restrict__ out_q,
        float* __restrict__ loss_acc,           // ws+0
        unsigned* __restrict__ ticket,          // ws+1
        float* __restrict__ out_loss) {
    const int tid  = threadIdx.x;
    const int wave = tid >> 6;
    const int lane = tid & 63;
    const int g    = blockIdx.x * 256 + tid;
    const int p    = g >> 1;                 // position
    const int h    = g & 1;                  // dim half (0: d<32, 1: d>=32)
    const int b    = p >> 12;
    const int hw   = p & (HWSZ - 1);

    // own half's 32 x values (coalesced: even/odd lanes form 2 segments)
    const float* xp = in + ((size_t)b << 18) + ((size_t)(h * 32) << 12) + hw;
    float xh[32];
    #pragma unroll
    for (int c = 0; c < 32; ++c) xh[c] = xp[(size_t)c << 12];

    const unsigned v  = __float_as_uint(out_idx[p]);
    int kk = (int)(v & 511u);
    const unsigned fl = v >> 27;

    if (fl) {
        // other half's 32 values
        float xo[32];
        const float* xp2 = in + ((size_t)b << 18)
                              + ((size_t)((1 - h) * 32) << 12) + hw;
        #pragma unroll
        for (int c = 0; c < 32; ++c) xo[c] = xp2[(size_t)c << 12];

        const int ia = (int)(v & 511u);
        const int ib = (int)((v >> 9) & 511u);
        const int ic = (int)((v >> 18) & 511u);
        float bu = 3.4e38f;
        int   bk = 0x7fffffff;

        // Branch-duplicated: static array identities only (no pointer select
        // -> arrays stay in registers; V8's `h ? xo : xh` spilled to scratch).
        // Both lanes run identical FP sequences -> identical kk.
        if (h == 0) {   // xh = dims 0..31, xo = dims 32..63
            const float x2 = np_sumsq64_split(xh, xo);
            if (fl & 4u) {
                for (int k = 0; k < 256; ++k) {
                    float u = exact_u_split2(xh, xo, x2, emb + (size_t)k * EMB,
                                             e2np[k]);
                    if (u < bu || (u == bu && k < bk)) { bu = u; bk = k; }
                }
            } else {
                float u1 = exact_u_split2(xh, xo, x2, emb + (size_t)ia * EMB,
                                          e2np[ia]);
                float u2 = exact_u_split2(xh, xo, x2, emb + (size_t)ib * EMB,
                                          e2np[ib]);
                if (u1 < u2 || (u1 == u2 && ia < ib)) { bu = u1; bk = ia; }
                else                                  { bu = u2; bk = ib; }
                if (fl & 2u) {
                    float u3 = exact_u_split2(xh, xo, x2,
                                              emb + (size_t)ic * EMB, e2np[ic]);
                    if (u3 < bu || (u3 == bu && ic < bk)) { bu = u3; bk = ic; }
                }
            }
        } else {        // xo = dims 0..31, xh = dims 32..63
            const float x2 = np_sumsq64_split(xo, xh);
            if (fl & 4u) {
                for (int k = 256; k < 512; ++k) {
                    float u = exact_u_split2(xo, xh, x2, emb + (size_t)k * EMB,
                                             e2np[k]);
                    if (u < bu || (u == bu && k < bk)) { bu = u; bk = k; }
                }
            } else {
                float u1 = exact_u_split2(xo, xh, x2, emb + (size_t)ia * EMB,
                                          e2np[ia]);
                float u2 = exact_u_split2(xo, xh, x2, emb + (size_t)ib * EMB,
                                          e2np[ib]);
                if (u1 < u2 || (u1 == u2 && ia < ib)) { bu = u1; bk = ia; }
                else                                  { bu = u2; bk = ib; }
                if (fl & 2u) {
                    float u3 = exact_u_split2(xo, xh, x2,
                                              emb + (size_t)ic * EMB, e2np[ic]);
                    if (u3 < bu || (u3 == bu && ic < bk)) { bu = u3; bk = ic; }
                }
            }
        }
        if (fl & 4u) {  // merge the pair-split half-scans (lane ^ 1 = pair)
            float ou = __shfl_xor(bu, 1, 64);
            int   ok = __shfl_xor(bk, 1, 64);
            if (ou < bu || (ou == bu && ok < bk)) { bu = ou; bk = ok; }
        }
        kk = bk;
    }

    // broadcast even lane's resolved index to the pair; write plain index
    kk = __shfl(kk, lane & ~1, 64);
    if (h == 0) out_idx[p] = (float)kk;

    // quantized output + loss partial over this half's 32 dims
    const float4* q4 = (const float4*)(emb + (size_t)kk * EMB + h * 32);
    float* op = out_q + ((size_t)b << 18) + ((size_t)(h * 32) << 12) + hw;
    float s = 0.0f;
    #pragma unroll
    for (int c4 = 0; c4 < 8; ++c4) {
        float4 q = q4[c4];
        float d0 = q.x - xh[c4 * 4 + 0];
        float d1 = q.y - xh[c4 * 4 + 1];
        float d2 = q.z - xh[c4 * 4 + 2];
        float d3 = q.w - xh[c4 * 4 + 3];
        s = fmaf(d0, d0, s); s = fmaf(d1, d1, s);
        s = fmaf(d2, d2, s); s = fmaf(d3, d3, s);
        op[(size_t)(c4 * 4 + 0) << 12] = q.x;
        op[(size_t)(c4 * 4 + 1) << 12] = q.y;
        op[(size_t)(c4 * 4 + 2) << 12] = q.z;
        op[(size_t)(c4 * 4 + 3) << 12] = q.w;
    }

    // loss: wave shuffle -> LDS -> one float atomicAdd per block -> ticket
    // (atomic order noise ~1e-7 << 7.6e-6 tolerance; V5-proven)
    #pragma unroll
    for (int off = 32; off > 0; off >>= 1)
        s += __shfl_down(s, off, 64);
    __shared__ float red[4];
    if (lane == 0) red[wave] = s;
    __syncthreads();
    if (tid == 0) {
        atomicAdd(loss_acc, (red[0] + red[1]) + (red[2] + red[3]));
        __threadfence();
        unsigned tk = atomicAdd(ticket, 1u);
        if (tk == 1023u) {
            float tot = atomicAdd(loss_acc, 0.0f);   // coherent final read
            out_loss[0] = 1.25f * tot * (1.0f / ((float)NPOS * (float)EMB));
        }
    }
}

extern "C" void kernel_launch(void* const* d_in, const int* in_sizes, int n_in,
                              void* d_out, int out_size, void* d_ws, size_t ws_size,
                              hipStream_t stream) {
    const float* in  = (const float*)d_in[0];
    const float* emb = (const float*)d_in[1];
    float* ws  = (float*)d_ws;
    float* out = (float*)d_out;

    float*    out_loss = out;
    float*    out_q    = out + 1;
    float*    out_idx  = out + 1 + (size_t)NPOS * EMB;
    float*    loss_acc = ws;                     // ws[0]
    unsigned* ticket   = (unsigned*)ws + 1;      // ws[1]
    float*    e2np     = ws + 1032;              // [512]
    short8*   bfrag    = (short8*)(ws + 1544);   // 128 KB

    vq_prep<<<16, 256, 0, stream>>>(emb, ws);
    vq_screen<<<NPOS / 64, 256, 0, stream>>>(in, e2np, bfrag, out_idx);
    vq_write<<<NPOS * 2 / 256, 256, 0, stream>>>(in, emb, e2np, out_idx, out_q,
                                                 loss_acc, ticket, out_loss);
}

// Round 10
// 319.613 us; speedup vs baseline: 1.2649x; 1.2649x over previous
//
#include <hip/hip_runtime.h>

// VQ-VAE VectorQuantizer: B=32, C=D=64, H=W=64, K=512
// d_in[0]: inputs  [32,64,64,64] f32 (NCHW, C = embedding dim)
// d_in[1]: embedding [512,64] f32
// d_out: [loss(1) | out(32*64*64*64) | indices(32*4096)] all read as f32
//
// V10: recombination of the two measured-best components from the ledger:
//  - screen: V6's pt=2 / launch_bounds(256,3) / register-prefetch MFMA sweep
//    (measured ~13-15us inside round-5's 203us total), upgraded top-3->top-4
//    so no separate full-scan kernel is needed.
//  - writer: round-5's 1-thread/position writer (measured 56us, VGPR 60,
//    970 GB/s) verbatim, with candidates decoded from out_idx bits instead
//    of LDS lists. g2 (~4%): 2 exact candidates; g3 (~0.2%): 3; g4 (~1e-5):
//    inline full 512-scan (same branch shape as the 56us measurement).
// The 2-thread/position writers (V7b/V8/V9: 162/230/280us) are abandoned:
// three register-regime diseases in a row (unrolled-coop VGPR=256, pointer-
// select scratch, branch-dup still serialized).
// Correctness (V8/V9-proven, passed twice): screen error on score
// differences <= ~1e-4 < DELTA=2.5e-4; numpy argmin is inside the candidate
// set unless the next g-flag escalates (strict-< INS4 makes boundary ties
// escalate). Exact path = round-0-proven fmaf/pairwise-8 ordering,
// lexicographic (u,k) min == numpy first-min.

#define KCODE 512
#define EMB   64
#define HWSZ  4096
#define NPOS  131072
#define DELTA 2.5e-4f

typedef short short8  __attribute__((ext_vector_type(8)));
typedef float float4v __attribute__((ext_vector_type(4)));

// ws float layout:
//   [1]           writer ticket (uint)
//   [8..519]      writer block partials (512)
//   [1032..1543]  e2 (numpy rounding, by code)
//   [1544..34311] bfrag short8[32][2][2][64] (128 KB)

// ---------- numpy-exact helpers ----------
__device__ __forceinline__ float np_sumsq64(const float* a) {
    #pragma clang fp contract(off)
    {
        float r0 = a[0] * a[0], r1 = a[1] * a[1], r2 = a[2] * a[2], r3 = a[3] * a[3];
        float r4 = a[4] * a[4], r5 = a[5] * a[5], r6 = a[6] * a[6], r7 = a[7] * a[7];
        for (int i = 8; i < 64; i += 8) {
            r0 += a[i + 0] * a[i + 0];
            r1 += a[i + 1] * a[i + 1];
            r2 += a[i + 2] * a[i + 2];
            r3 += a[i + 3] * a[i + 3];
            r4 += a[i + 4] * a[i + 4];
            r5 += a[i + 5] * a[i + 5];
            r6 += a[i + 6] * a[i + 6];
            r7 += a[i + 7] * a[i + 7];
        }
        return ((r0 + r1) + (r2 + r3)) + ((r4 + r5) + (r6 + r7));
    }
}

// exact numpy distance: u = fl(fl(x2 - 2*xe) + e2k)  (round-0-proven order)
__device__ __forceinline__ float exact_u(const float* x, float x2,
                                         const float* ek, float e2k) {
    float t0 = 0.f, t1 = 0.f, t2 = 0.f, t3 = 0.f;
    #pragma unroll
    for (int c = 0; c < EMB; c += 4) {
        t0 = fmaf(x[c + 0], ek[c + 0], t0);
        t1 = fmaf(x[c + 1], ek[c + 1], t1);
        t2 = fmaf(x[c + 2], ek[c + 2], t2);
        t3 = fmaf(x[c + 3], ek[c + 3], t3);
    }
    float xe  = (t0 + t1) + (t2 + t3);
    float tmp = x2 - 2.0f * xe;     // 2*xe exact -> contraction rounding-identical
    return tmp + e2k;
}

__device__ __forceinline__ unsigned short bf16rne(float f) {
    unsigned u = __float_as_uint(f);
    unsigned r = (u + 0x7FFFu + ((u >> 16) & 1u)) >> 16;
    return (unsigned short)r;
}
__device__ __forceinline__ float bf16tof(unsigned short h) {
    return __uint_as_float((unsigned)h << 16);
}

// sorted-insert of (v,i) into ((M1,I1),(M2,I2),(M3,I3),M4); strict < keeps
// earlier element on ties (boundary ties escalate the next g-flag instead).
#define INS4(M1, I1, M2, I2, M3, I3, M4, v, i)                       \
    {                                                                \
        bool lt1 = (v) < (M1), lt2 = (v) < (M2);                     \
        bool lt3 = (v) < (M3), lt4 = (v) < (M4);                     \
        (M4) = lt3 ? (M3) : (lt4 ? (v) : (M4));                      \
        (I3) = lt2 ? (I2) : (lt3 ? (i) : (I3));                      \
        (M3) = lt2 ? (M2) : (lt3 ? (v) : (M3));                      \
        (I2) = lt1 ? (I1) : (lt2 ? (i) : (I2));                      \
        (M2) = lt1 ? (M1) : (lt2 ? (v) : (M2));                      \
        (I1) = lt1 ? (i) : (I1);                                     \
        (M1) = lt1 ? (v) : (M1);                                     \
    }

// ---------- prep: e2 + bfrag + ticket zero ----------
__global__ void vq_prep(const float* __restrict__ emb, float* __restrict__ ws) {
    int f = blockIdx.x * blockDim.x + threadIdx.x;   // 0..4095
    if (f == 0) { ((unsigned*)ws)[0] = 0u; ((unsigned*)ws)[1] = 0u; }
    if (f < KCODE) ws[1032 + f] = np_sumsq64(emb + f * EMB);
    short8* bfrag = (short8*)(ws + 1544);
    int l = f & 63;
    int c = (f >> 6) & 1;
    int t = f >> 7;            // 0..31
    int code  = t * 16 + (l & 15);
    int dbase = 32 * c + ((l >> 4) & 3) * 8;
    const float* e = emb + code * EMB + dbase;
    short8 h, lo;
    #pragma unroll
    for (int j = 0; j < 8; ++j) {
        float v = e[j];
        unsigned short hb = bf16rne(v);
        float hf = bf16tof(hb);
        unsigned short lb = bf16rne(v - hf);
        h[j]  = (short)hb;
        lo[j] = (short)lb;
    }
    bfrag[t * 256 + c * 128 + 0 * 64 + l] = h;
    bfrag[t * 256 + c * 128 + 1 * 64 + l] = lo;
}

// ---------- screen: pt=2 MFMA sweep (V6 shape), top-4 tracking ----------
__global__ __launch_bounds__(256, 3) void vq_screen(
        const float*  __restrict__ in,
        const float*  __restrict__ e2np,      // ws+1032
        const short8* __restrict__ bfrag,     // ws+1544
        float*        __restrict__ out_idx) { // bit-packed {i1,i2,i3,flags}
    const int tid  = threadIdx.x;
    const int wave = tid >> 6;
    const int lane = tid & 63;
    const int lg   = lane >> 4;
    const int lc   = lane & 15;
    const int wavePos = blockIdx.x * 128 + wave * 32;

    // A-fragments: 2 pos-tiles x 2 dim-chunks, hi/lo of g = -2x.
    // A element j of lane: row = lane&15 (position), k-dim = (lane>>4)*8+j.
    short8 fH[2][2], fL[2][2];
    #pragma unroll
    for (int pt = 0; pt < 2; ++pt) {
        int pos = wavePos + pt * 16 + lc;
        int b   = pos >> 12;
        int hw  = pos & (HWSZ - 1);
        const float* xb = in + ((size_t)b << 18) + hw;
        #pragma unroll
        for (int c = 0; c < 2; ++c) {
            short8 h, lo;
            #pragma unroll
            for (int j = 0; j < 8; ++j) {
                int d = 32 * c + lg * 8 + j;
                float g = -2.0f * xb[(size_t)d << 12];
                unsigned short hb = bf16rne(g);
                float hf = bf16tof(hb);
                unsigned short lb = bf16rne(g - hf);
                h[j]  = (short)hb;
                lo[j] = (short)lb;
            }
            fH[pt][c] = h;
            fL[pt][c] = lo;
        }
    }

    float m1[2][4], m2[2][4], m3[2][4], m4[2][4];
    int   i1[2][4], i2[2][4], i3[2][4];
    #pragma unroll
    for (int pt = 0; pt < 2; ++pt)
        #pragma unroll
        for (int r = 0; r < 4; ++r) {
            m1[pt][r] = 3.4e38f; m2[pt][r] = 3.4e38f;
            m3[pt][r] = 3.4e38f; m4[pt][r] = 3.4e38f;
            i1[pt][r] = 0; i2[pt][r] = 0; i3[pt][r] = 0;
        }

    short8 ceh0 = bfrag[lane],       cel0 = bfrag[64 + lane];
    short8 ceh1 = bfrag[128 + lane], cel1 = bfrag[192 + lane];
    float  ce2  = e2np[lc];
    #pragma unroll 2
    for (int t = 0; t < 32; ++t) {
        short8 neh0, nel0, neh1, nel1;
        float  ne2 = 0.0f;
        if (t < 31) {
            const short8* nb = bfrag + (t + 1) * 256;
            neh0 = nb[lane];       nel0 = nb[64 + lane];
            neh1 = nb[128 + lane]; nel1 = nb[192 + lane];
            ne2  = e2np[(t + 1) * 16 + lc];
        }
        const int kf = t * 16 + lc;
        #pragma unroll
        for (int pt = 0; pt < 2; ++pt) {
            float4v aH = {ce2, ce2, ce2, ce2};
            float4v aM = {0.f, 0.f, 0.f, 0.f};
            float4v aL = {0.f, 0.f, 0.f, 0.f};
            aH = __builtin_amdgcn_mfma_f32_16x16x32_bf16(fH[pt][0], ceh0, aH, 0, 0, 0);
            aM = __builtin_amdgcn_mfma_f32_16x16x32_bf16(fH[pt][0], cel0, aM, 0, 0, 0);
            aL = __builtin_amdgcn_mfma_f32_16x16x32_bf16(fL[pt][0], ceh0, aL, 0, 0, 0);
            aH = __builtin_amdgcn_mfma_f32_16x16x32_bf16(fH[pt][1], ceh1, aH, 0, 0, 0);
            aM = __builtin_amdgcn_mfma_f32_16x16x32_bf16(fH[pt][1], cel1, aM, 0, 0, 0);
            aL = __builtin_amdgcn_mfma_f32_16x16x32_bf16(fL[pt][1], ceh1, aL, 0, 0, 0);
            #pragma unroll
            for (int r = 0; r < 4; ++r) {
                float sv = (aH[r] + aM[r]) + aL[r];
                INS4(m1[pt][r], i1[pt][r], m2[pt][r], i2[pt][r],
                     m3[pt][r], i3[pt][r], m4[pt][r], sv, kf);
            }
        }
        ceh0 = neh0; cel0 = nel0; ceh1 = neh1; cel1 = nel1; ce2 = ne2;
    }

    // cross-lane top-4 merge over the 16-lane code group. Partner's m4 can
    // never rank <=3 in the union (its own m1..m3 are smaller), so value-only
    // min into M4 after the three indexed inserts is exact.
    #pragma unroll
    for (int pt = 0; pt < 2; ++pt) {
        #pragma unroll
        for (int r = 0; r < 4; ++r) {
            float M1 = m1[pt][r], M2 = m2[pt][r], M3 = m3[pt][r], M4 = m4[pt][r];
            int   I1 = i1[pt][r], I2 = i2[pt][r], I3 = i3[pt][r];
            #pragma unroll
            for (int d = 1; d <= 8; d <<= 1) {
                float pm1 = __shfl_xor(M1, d, 64);
                int   pi1 = __shfl_xor(I1, d, 64);
                float pm2 = __shfl_xor(M2, d, 64);
                int   pi2 = __shfl_xor(I2, d, 64);
                float pm3 = __shfl_xor(M3, d, 64);
                int   pi3 = __shfl_xor(I3, d, 64);
                float pm4 = __shfl_xor(M4, d, 64);
                INS4(M1, I1, M2, I2, M3, I3, M4, pm1, pi1);
                INS4(M1, I1, M2, I2, M3, I3, M4, pm2, pi2);
                INS4(M1, I1, M2, I2, M3, I3, M4, pm3, pi3);
                M4 = fminf(M4, pm4);
            }
            m1[pt][r] = M1; m2[pt][r] = M2; m3[pt][r] = M3; m4[pt][r] = M4;
            i1[pt][r] = I1; i2[pt][r] = I2; i3[pt][r] = I3;
        }
    }

    if (lc == 0) {
        #pragma unroll
        for (int pt = 0; pt < 2; ++pt) {
            #pragma unroll
            for (int r = 0; r < 4; ++r) {
                int p = wavePos + pt * 16 + lg * 4 + r;
                unsigned g2 = (m2[pt][r] - m1[pt][r] <= DELTA) ? 1u : 0u;
                unsigned g3 = (m3[pt][r] - m1[pt][r] <= DELTA) ? 1u : 0u;
                unsigned g4 = (m4[pt][r] - m1[pt][r] <= DELTA) ? 1u : 0u;
                unsigned packed = (unsigned)i1[pt][r]
                                | ((unsigned)i2[pt][r] << 9)
                                | ((unsigned)i3[pt][r] << 18)
                                | (g2 << 27) | (g3 << 28) | (g4 << 29);
                out_idx[p] = __uint_as_float(packed);   // bit store, not cast
            }
        }
    }
}

// ---------- writer: round-5's measured-56us shape, bit-decoded candidates --
__global__ __launch_bounds__(256) void vq_write(
        const float* __restrict__ in, const float* __restrict__ emb,
        const float* __restrict__ e2np,
        float* __restrict__ out_idx, float* __restrict__ out_q,
        float* __restrict__ partials,           // ws+8, [512]
        unsigned* __restrict__ ticket,          // ws+1
        float* __restrict__ out_loss) {
    const int tid = threadIdx.x;
    const int n   = blockIdx.x * 256 + tid;
    const int b   = n >> 12;
    const int hw  = n & (HWSZ - 1);

    const float* xp = in + ((size_t)b << 18) + hw;
    float x[EMB];
    #pragma unroll
    for (int c = 0; c < EMB; ++c) x[c] = xp[(size_t)c << 12];

    const unsigned v  = __float_as_uint(out_idx[n]);
    int kk = (int)(v & 511u);
    const unsigned fl = v >> 27;
    if (fl) {
        float x2 = np_sumsq64(x);
        if (fl & 4u) {
            // g4 (~1e-5 of positions): exact full scan, first-min semantics
            float bu = 3.4e38f; int bk = 0;
            for (int k = 0; k < KCODE; ++k) {
                float u = exact_u(x, x2, emb + k * EMB, e2np[k]);
                if (u < bu) { bu = u; bk = k; }
            }
            kk = bk;
        } else {
            // g2/g3: 2-3 candidate exact rescore, lexicographic (u,k)
            int ia = (int)(v & 511u), ib = (int)((v >> 9) & 511u);
            float u1 = exact_u(x, x2, emb + ia * EMB, e2np[ia]);
            float u2 = exact_u(x, x2, emb + ib * EMB, e2np[ib]);
            float bu; int bk;
            if (u1 < u2 || (u1 == u2 && ia < ib)) { bu = u1; bk = ia; }
            else                                  { bu = u2; bk = ib; }
            if (fl & 2u) {
                int ic = (int)((v >> 18) & 511u);
                float u3 = exact_u(x, x2, emb + ic * EMB, e2np[ic]);
                if (u3 < bu || (u3 == bu && ic < bk)) { bk = ic; }
            }
            kk = bk;
        }
    }
    out_idx[n] = (float)kk;

    // quantized output + per-thread (q-x)^2 partial (round-5 shape)
    const float4* qk = (const float4*)(emb + (size_t)kk * EMB);
    float* op = out_q + ((size_t)b << 18) + hw;
    float s = 0.0f;
    #pragma unroll
    for (int c4 = 0; c4 < EMB / 4; ++c4) {
        float4 q = qk[c4];
        float d0 = q.x - x[c4 * 4 + 0];
        float d1 = q.y - x[c4 * 4 + 1];
        float d2 = q.z - x[c4 * 4 + 2];
        float d3 = q.w - x[c4 * 4 + 3];
        s = fmaf(d0, d0, s); s = fmaf(d1, d1, s);
        s = fmaf(d2, d2, s); s = fmaf(d3, d3, s);
        op[(size_t)(c4 * 4 + 0) << 12] = q.x;
        op[(size_t)(c4 * 4 + 1) << 12] = q.y;
        op[(size_t)(c4 * 4 + 2) << 12] = q.z;
        op[(size_t)(c4 * 4 + 3) << 12] = q.w;
    }

    // loss: wave shuffle -> LDS -> block partial -> last-block ticket
    #pragma unroll
    for (int off = 32; off > 0; off >>= 1)
        s += __shfl_down(s, off, 64);
    __shared__ float red[4];
    const int wave = tid >> 6;
    const int lane = tid & 63;
    if (lane == 0) red[wave] = s;
    __syncthreads();
    if (tid == 0) {
        partials[blockIdx.x] = (red[0] + red[1]) + (red[2] + red[3]);
        __threadfence();
        unsigned tk = atomicAdd(ticket, 1u);
        if (tk == 511u) {
            __threadfence();
            float a0 = 0.f, a1 = 0.f, a2 = 0.f, a3 = 0.f;
            float a4 = 0.f, a5 = 0.f, a6 = 0.f, a7 = 0.f;
            for (int i = 0; i < 512; i += 8) {
                a0 += partials[i + 0]; a1 += partials[i + 1];
                a2 += partials[i + 2]; a3 += partials[i + 3];
                a4 += partials[i + 4]; a5 += partials[i + 5];
                a6 += partials[i + 6]; a7 += partials[i + 7];
            }
            float tot = ((a0 + a1) + (a2 + a3)) + ((a4 + a5) + (a6 + a7));
            out_loss[0] = 1.25f * tot * (1.0f / ((float)NPOS * (float)EMB));
        }
    }
}

extern "C" void kernel_launch(void* const* d_in, const int* in_sizes, int n_in,
                              void* d_out, int out_size, void* d_ws, size_t ws_size,
                              hipStream_t stream) {
    const float* in  = (const float*)d_in[0];
    const float* emb = (const float*)d_in[1];
    float* ws  = (float*)d_ws;
    float* out = (float*)d_out;

    float*    out_loss = out;
    float*    out_q    = out + 1;
    float*    out_idx  = out + 1 + (size_t)NPOS * EMB;
    unsigned* ticket   = (unsigned*)ws + 1;      // ws[1]
    float*    partials = ws + 8;                 // [512]
    float*    e2np     = ws + 1032;              // [512]
    short8*   bfrag    = (short8*)(ws + 1544);   // 128 KB

    vq_prep<<<16, 256, 0, stream>>>(emb, ws);
    vq_screen<<<NPOS / 128, 256, 0, stream>>>(in, e2np, bfrag, out_idx);
    vq_write<<<NPOS / 256, 256, 0, stream>>>(in, emb, e2np, out_idx, out_q,
                                             partials, ticket, out_loss);
}